// Round 3
// baseline (654.105 us; speedup 1.0000x reference)
//
#include <hip/hip_runtime.h>

typedef __attribute__((ext_vector_type(8))) short s8v;
typedef __attribute__((ext_vector_type(4))) short s4v;
typedef __attribute__((ext_vector_type(4))) float f4v;

#define DEV __device__ __forceinline__

DEV short b16(float f) {
  unsigned u = __builtin_bit_cast(unsigned, f);
  u = (u + 0x7fffu + ((u >> 16) & 1u)) >> 16;
  return (short)u;
}

// packed f32x2 -> bf16x2 (RNE) as one uint
DEV unsigned pk2(float a, float b) {
#if __has_builtin(__builtin_amdgcn_cvt_pk_bf16_f32)
  auto p = __builtin_amdgcn_cvt_pk_bf16_f32(a, b);
  return __builtin_bit_cast(unsigned, p);
#else
  return (unsigned)(unsigned short)b16(a) | ((unsigned)(unsigned short)b16(b) << 16);
#endif
}

DEV float fexp2(float x) {
#if __has_builtin(__builtin_amdgcn_exp2f)
  return __builtin_amdgcn_exp2f(x);
#else
  return exp2f(x);
#endif
}

// async global->LDS, 16B per lane; lds base must be wave-uniform
DEV void gl_lds16(const short* g, short* l) {
  __builtin_amdgcn_global_load_lds((const __attribute__((address_space(1))) void*)g,
                                   (__attribute__((address_space(3))) void*)l, 16, 0, 0);
}

// ---------------- cast x: fp32 -> bf16
__global__ __launch_bounds__(256) void cast_f32_bf16(const float* __restrict__ in,
                                                     short* __restrict__ out, int n4) {
  int i = blockIdx.x * 256 + threadIdx.x;
  if (i >= n4) return;
  float4 v = ((const float4*)in)[i];
  s4v o; o.x = b16(v.x); o.y = b16(v.y); o.z = b16(v.z); o.w = b16(v.w);
  ((s4v*)out)[i] = o;
}

// ---------------- transpose-cast W [1024 k][1024 n] fp32 -> Wt [n][k] bf16
__global__ __launch_bounds__(256) void wtrans(const float* __restrict__ W, short* __restrict__ Wt) {
  int id = blockIdx.x * 256 + threadIdx.x;
  int k8 = id >> 10;
  int n  = id & 1023;
  s8v o;
#pragma unroll
  for (int j = 0; j < 8; ++j) o[j] = b16(W[(k8 * 8 + j) * 1024 + n]);
  *(s8v*)&Wt[n * 1024 + k8 * 8] = o;
}

// ---------------- GEMM: C[8192x1024] = A(bf16) x Bt^T + bias; global_load_lds staging
template <bool OUT_BF16>
__global__ __launch_bounds__(256) void gemm128(const short* __restrict__ A,
                                               const short* __restrict__ Bt,
                                               const float* __restrict__ bias,
                                               void* __restrict__ Cout) {
  __shared__ short As[128 * 64];
  __shared__ short Bs[128 * 64];
  const int tid = threadIdx.x;
  const int w = tid >> 6, lane = tid & 63, quad = lane >> 4, l15 = lane & 15;
  const int wm = w >> 1, wn = w & 1;
  const int m0 = blockIdx.y * 128, n0 = blockIdx.x * 128;
  const int lr = lane >> 3, lc = (lane & 7) * 8;
  f4v acc[4][4] = {};
  for (int k0 = 0; k0 < 1024; k0 += 64) {
#pragma unroll
    for (int i = 0; i < 4; ++i) {
      int c = i * 4 + w;
      int r = c * 8 + lr;
      gl_lds16(&A[(m0 + r) * 1024 + k0 + lc], &As[c * 512]);
      gl_lds16(&Bt[(n0 + r) * 1024 + k0 + lc], &Bs[c * 512]);
    }
    __syncthreads();
#pragma unroll
    for (int kk = 0; kk < 2; ++kk) {
      s8v af[4], bf[4];
#pragma unroll
      for (int mt = 0; mt < 4; ++mt) af[mt] = *(const s8v*)&As[(wm * 64 + mt * 16 + l15) * 64 + kk * 32 + quad * 8];
#pragma unroll
      for (int nt = 0; nt < 4; ++nt) bf[nt] = *(const s8v*)&Bs[(wn * 64 + nt * 16 + l15) * 64 + kk * 32 + quad * 8];
#pragma unroll
      for (int mt = 0; mt < 4; ++mt)
#pragma unroll
        for (int nt = 0; nt < 4; ++nt)
          acc[mt][nt] = __builtin_amdgcn_mfma_f32_16x16x32_bf16(af[mt], bf[nt], acc[mt][nt], 0, 0, 0);
    }
    __syncthreads();
  }
#pragma unroll
  for (int nt = 0; nt < 4; ++nt) {
    const int col = n0 + wn * 64 + nt * 16 + l15;
    const float bcol = bias[col];
#pragma unroll
    for (int mt = 0; mt < 4; ++mt)
#pragma unroll
      for (int r = 0; r < 4; ++r) {
        const int row = m0 + wm * 64 + mt * 16 + quad * 4 + r;
        float v = acc[mt][nt][r] + bcol;
        if (OUT_BF16) ((short*)Cout)[row * 1024 + col] = b16(v);
        else          ((float*)Cout)[row * 1024 + col] = v;
      }
  }
}

// ---------------- V transpose: Vb [b,s,h,d] -> Vt [b,h,d,s]
__global__ __launch_bounds__(256) void vtrans(const short* __restrict__ V, short* __restrict__ Vt) {
  __shared__ short T[128][72];
  const int st = blockIdx.x, h = blockIdx.y, b = blockIdx.z;
  const int tid = threadIdx.x;
#pragma unroll
  for (int i = 0; i < 4; ++i) {
    int c = tid + i * 256;
    int r = c >> 3, c8 = (c & 7) * 8;
    *(s8v*)&T[r][c8] = *(const s8v*)&V[((b * 2048 + st * 128 + r) * 16 + h) * 64 + c8];
  }
  __syncthreads();
#pragma unroll
  for (int i = 0; i < 4; ++i) {
    int id = tid + i * 256;
    int d = id & 63, s8 = id >> 6;
    s8v o;
#pragma unroll
    for (int j = 0; j < 8; ++j) o[j] = T[s8 * 8 + j][d];
    *(s8v*)&Vt[((b * 16 + h) * 64 + d) * 2048 + st * 128 + s8 * 8] = o;
  }
}

// ---------------- fused attention v3: zero barriers, direct-global fragments.
// Block = 4 waves, each wave owns 32 q rows end-to-end. Only LDS: P transpose
// buffer (wave-private rows, double-buffered 64-k chunks).
__global__ __launch_bounds__(256, 4) void attn_ctx(const short* __restrict__ Q, const short* __restrict__ K,
                                                   const short* __restrict__ Vt,
                                                   float* __restrict__ rbuf, short* __restrict__ ctx) {
  __shared__ short Ps[2][128][72];   // 36864 B
  const int q128 = blockIdx.x, h = blockIdx.y, b = blockIdx.z;
  const int tid = threadIdx.x, w = tid >> 6, lane = tid & 63, quad = lane >> 4, l15 = lane & 15;
  const int bh = b * 16 + h;
  const int q0 = q128 * 128;
  const float C2 = 0.18033688011f;   // (1/8) * log2(e)

  // Q fragments (B-operand of St = K·Q^T) straight from global
  s8v qf[2][2];
#pragma unroll
  for (int qt = 0; qt < 2; ++qt) {
    const short* qp = &Q[((b * 2048 + q0 + w * 32 + qt * 16 + l15) * 16 + h) * 64];
    qf[qt][0] = *(const s8v*)&qp[quad * 8];
    qf[qt][1] = *(const s8v*)&qp[32 + quad * 8];
  }
  const short* kp = &K[((long)(b * 2048) * 16 + h) * 64];
  const short* vp = &Vt[(long)(bh * 64) * 2048];

  f4v o[2][4] = {};
  float l_acc[2] = {0.f, 0.f};

  for (int c = 0; c < 32; ++c) {     // 64-k chunks
    const int k0 = c * 64;
    short (*P)[72] = Ps[c & 1];
    // ---- score phase: 4 ktiles of 16 k
#pragma unroll
    for (int t = 0; t < 4; ++t) {
      const short* kr = kp + (k0 + t * 16 + l15) * 1024;
      s8v a0 = *(const s8v*)&kr[quad * 8];
      s8v a1 = *(const s8v*)&kr[32 + quad * 8];
#pragma unroll
      for (int qt = 0; qt < 2; ++qt) {
        f4v st = {};
        st = __builtin_amdgcn_mfma_f32_16x16x32_bf16(a0, qf[qt][0], st, 0, 0, 0);
        st = __builtin_amdgcn_mfma_f32_16x16x32_bf16(a1, qf[qt][1], st, 0, 0, 0);
        float e0 = fexp2(st[0] * C2), e1 = fexp2(st[1] * C2);
        float e2 = fexp2(st[2] * C2), e3 = fexp2(st[3] * C2);
        l_acc[qt] += (e0 + e1) + (e2 + e3);
        uint2 pp; pp.x = pk2(e0, e1); pp.y = pk2(e2, e3);
        *(uint2*)&P[w * 32 + qt * 16 + l15][t * 16 + quad * 4] = pp;
      }
    }
    // ---- PV phase: O += P · V  (only this wave's P rows -> no barrier)
#pragma unroll
    for (int s = 0; s < 2; ++s) {
      s8v vb[4];
#pragma unroll
      for (int dt = 0; dt < 4; ++dt)
        vb[dt] = *(const s8v*)&vp[(dt * 16 + l15) * 2048 + k0 + s * 32 + quad * 8];
#pragma unroll
      for (int qt = 0; qt < 2; ++qt) {
        s8v a = *(const s8v*)&P[w * 32 + qt * 16 + l15][s * 32 + quad * 8];
#pragma unroll
        for (int dt = 0; dt < 4; ++dt)
          o[qt][dt] = __builtin_amdgcn_mfma_f32_16x16x32_bf16(a, vb[dt], o[qt][dt], 0, 0, 0);
      }
    }
  }

  // ---- finalize: reduce l across quads (shfl only), write 1/l, normalize O
#pragma unroll
  for (int qt = 0; qt < 2; ++qt) {
    float ls = l_acc[qt];
    ls += __shfl_xor(ls, 16, 64);
    ls += __shfl_xor(ls, 32, 64);
    float rv = 1.0f / ls;           // valid in every lane for q = w*32+qt*16+l15
    if (quad == 0) rbuf[bh * 2048 + q0 + w * 32 + qt * 16 + l15] = rv;
    float rvq[4];
#pragma unroll
    for (int r = 0; r < 4; ++r) rvq[r] = __shfl(rv, quad * 4 + r, 16);
#pragma unroll
    for (int dt = 0; dt < 4; ++dt)
#pragma unroll
      for (int r = 0; r < 4; ++r) {
        int s = q0 + w * 32 + qt * 16 + quad * 4 + r;
        ctx[((b * 2048 + s) * 16 + h) * 64 + dt * 16 + l15] = b16(o[qt][dt][r] * rvq[r]);
      }
  }
}

// ---------------- mean over heads of probs -> [b, q, k] fp32. Zero LDS, zero barriers.
__global__ __launch_bounds__(256, 4) void mean_probs(const short* __restrict__ Q, const short* __restrict__ K,
                                                     const float* __restrict__ rbuf, float* __restrict__ outm) {
  const int k128 = blockIdx.x, q128 = blockIdx.y, b = blockIdx.z;
  const int tid = threadIdx.x, w = tid >> 6, lane = tid & 63, quad = lane >> 4, l15 = lane & 15;
  const int q0 = q128 * 128;
  const float C2 = 0.18033688011f;
  f4v mn[2][8] = {};
  for (int h = 0; h < 16; ++h) {
    // Q fragments (B-operand), rows w*32+qt*16+l15
    s8v qf[2][2];
#pragma unroll
    for (int qt = 0; qt < 2; ++qt) {
      const short* qp = &Q[((b * 2048 + q0 + w * 32 + qt * 16 + l15) * 16 + h) * 64];
      qf[qt][0] = *(const s8v*)&qp[quad * 8];
      qf[qt][1] = *(const s8v*)&qp[32 + quad * 8];
    }
    float rr[2];
#pragma unroll
    for (int qt = 0; qt < 2; ++qt)
      rr[qt] = rbuf[(b * 16 + h) * 2048 + q0 + w * 32 + qt * 16 + l15] * 0.0625f;
    const short* kp = &K[((long)(b * 2048 + k128 * 128) * 16 + h) * 64];
#pragma unroll
    for (int t = 0; t < 8; ++t) {
      const short* kr = kp + (t * 16 + l15) * 1024;
      s8v a0 = *(const s8v*)&kr[quad * 8];
      s8v a1 = *(const s8v*)&kr[32 + quad * 8];
#pragma unroll
      for (int qt = 0; qt < 2; ++qt) {
        f4v st = {};
        st = __builtin_amdgcn_mfma_f32_16x16x32_bf16(a0, qf[qt][0], st, 0, 0, 0);
        st = __builtin_amdgcn_mfma_f32_16x16x32_bf16(a1, qf[qt][1], st, 0, 0, 0);
#pragma unroll
        for (int r = 0; r < 4; ++r)
          mn[qt][t][r] += fexp2(st[r] * C2) * rr[qt];
      }
    }
  }
  // write: lane holds q = q0 + w*32 + qt*16 + l15, k = k128*128 + t*16 + quad*4 + r
#pragma unroll
  for (int qt = 0; qt < 2; ++qt) {
    const long qrow = q0 + w * 32 + qt * 16 + l15;
    float* op = &outm[((long)b * 2048 + qrow) * 2048 + k128 * 128 + quad * 4];
#pragma unroll
    for (int t = 0; t < 8; ++t)
      *(f4v*)&op[t * 16] = mn[qt][t];
  }
}

extern "C" void kernel_launch(void* const* d_in, const int* in_sizes, int n_in,
                              void* d_out, int out_size, void* d_ws, size_t ws_size,
                              hipStream_t stream) {
  (void)in_sizes; (void)n_in; (void)out_size; (void)ws_size;
  const float* x  = (const float*)d_in[0];
  const float* Wq = (const float*)d_in[1];
  const float* bq = (const float*)d_in[2];
  const float* Wk = (const float*)d_in[3];
  const float* bk = (const float*)d_in[4];
  const float* Wv = (const float*)d_in[5];
  const float* bv = (const float*)d_in[6];
  const float* Wo = (const float*)d_in[7];
  const float* bo = (const float*)d_in[8];
  float* out  = (float*)d_out;
  float* outm = out + 8388608;

  char* ws = (char*)d_ws;
  short* xb  = (short*)(ws);                 // 16 MB (reused as ctx)
  short* Wqt = (short*)(ws + 16777216);
  short* Wkt = (short*)(ws + 18874368);
  short* Wvt = (short*)(ws + 20971520);
  short* Wot = (short*)(ws + 23068672);
  short* Qb  = (short*)(ws + 25165824);      // 16 MB
  short* Kb  = (short*)(ws + 41943040);      // 16 MB
  short* Vb  = (short*)(ws + 58720256);      // 16 MB (dead after vtrans)
  short* Vt  = (short*)(ws + 75497472);      // 16 MB
  float* rbuf = (float*)Vb;                  // 512 KB alias in dead Vb
  short* ctx = xb;                           // alias: xb dead after QKV GEMMs

  cast_f32_bf16<<<8192, 256, 0, stream>>>(x, xb, 2097152);
  wtrans<<<512, 256, 0, stream>>>(Wq, Wqt);
  wtrans<<<512, 256, 0, stream>>>(Wk, Wkt);
  wtrans<<<512, 256, 0, stream>>>(Wv, Wvt);
  wtrans<<<512, 256, 0, stream>>>(Wo, Wot);
  dim3 gg(8, 64);
  gemm128<true><<<gg, 256, 0, stream>>>(xb, Wqt, bq, Qb);
  gemm128<true><<<gg, 256, 0, stream>>>(xb, Wkt, bk, Kb);
  gemm128<true><<<gg, 256, 0, stream>>>(xb, Wvt, bv, Vb);
  vtrans<<<dim3(16, 16, 4), 256, 0, stream>>>(Vb, Vt);
  attn_ctx<<<dim3(16, 16, 4), 256, 0, stream>>>(Qb, Kb, Vt, rbuf, ctx);
  mean_probs<<<dim3(16, 16, 4), 256, 0, stream>>>(Qb, Kb, rbuf, outm);
  gemm128<false><<<gg, 256, 0, stream>>>(ctx, Wot, bo, out);
}

// Round 4
// 461.948 us; speedup vs baseline: 1.4160x; 1.4160x over previous
//
#include <hip/hip_runtime.h>

typedef __attribute__((ext_vector_type(8))) short s8v;
typedef __attribute__((ext_vector_type(4))) short s4v;
typedef __attribute__((ext_vector_type(4))) float f4v;

#define DEV __device__ __forceinline__

DEV short b16(float f) {
  unsigned u = __builtin_bit_cast(unsigned, f);
  u = (u + 0x7fffu + ((u >> 16) & 1u)) >> 16;
  return (short)u;
}

// packed f32x2 -> bf16x2 (RNE) as one uint
DEV unsigned pk2(float a, float b) {
#if __has_builtin(__builtin_amdgcn_cvt_pk_bf16_f32)
  auto p = __builtin_amdgcn_cvt_pk_bf16_f32(a, b);
  return __builtin_bit_cast(unsigned, p);
#else
  return (unsigned)(unsigned short)b16(a) | ((unsigned)(unsigned short)b16(b) << 16);
#endif
}

DEV float fexp2(float x) {
#if __has_builtin(__builtin_amdgcn_exp2f)
  return __builtin_amdgcn_exp2f(x);
#else
  return exp2f(x);
#endif
}

// async global->LDS, 16B per lane; lds base must be wave-uniform
DEV void gl_lds16(const short* g, short* l) {
  __builtin_amdgcn_global_load_lds((const __attribute__((address_space(1))) void*)g,
                                   (__attribute__((address_space(3))) void*)l, 16, 0, 0);
}

// ---------------- cast x: fp32 -> bf16
__global__ __launch_bounds__(256) void cast_f32_bf16(const float* __restrict__ in,
                                                     short* __restrict__ out, int n4) {
  int i = blockIdx.x * 256 + threadIdx.x;
  if (i >= n4) return;
  float4 v = ((const float4*)in)[i];
  s4v o; o.x = b16(v.x); o.y = b16(v.y); o.z = b16(v.z); o.w = b16(v.w);
  ((s4v*)out)[i] = o;
}

// ---------------- transpose-cast W [1024 k][1024 n] fp32 -> Wt [n][k] bf16
__global__ __launch_bounds__(256) void wtrans(const float* __restrict__ W, short* __restrict__ Wt) {
  int id = blockIdx.x * 256 + threadIdx.x;
  int k8 = id >> 10;
  int n  = id & 1023;
  s8v o;
#pragma unroll
  for (int j = 0; j < 8; ++j) o[j] = b16(W[(k8 * 8 + j) * 1024 + n]);
  *(s8v*)&Wt[n * 1024 + k8 * 8] = o;
}

// ---------------- GEMM: C[8192x1024] = A(bf16) x Bt^T + bias; global_load_lds staging
template <bool OUT_BF16>
__global__ __launch_bounds__(256) void gemm128(const short* __restrict__ A,
                                               const short* __restrict__ Bt,
                                               const float* __restrict__ bias,
                                               void* __restrict__ Cout) {
  __shared__ short As[128 * 64];
  __shared__ short Bs[128 * 64];
  const int tid = threadIdx.x;
  const int w = tid >> 6, lane = tid & 63, quad = lane >> 4, l15 = lane & 15;
  const int wm = w >> 1, wn = w & 1;
  const int m0 = blockIdx.y * 128, n0 = blockIdx.x * 128;
  const int lr = lane >> 3, lc = (lane & 7) * 8;
  f4v acc[4][4] = {};
  for (int k0 = 0; k0 < 1024; k0 += 64) {
#pragma unroll
    for (int i = 0; i < 4; ++i) {
      int c = i * 4 + w;
      int r = c * 8 + lr;
      gl_lds16(&A[(m0 + r) * 1024 + k0 + lc], &As[c * 512]);
      gl_lds16(&Bt[(n0 + r) * 1024 + k0 + lc], &Bs[c * 512]);
    }
    __syncthreads();
#pragma unroll
    for (int kk = 0; kk < 2; ++kk) {
      s8v af[4], bf[4];
#pragma unroll
      for (int mt = 0; mt < 4; ++mt) af[mt] = *(const s8v*)&As[(wm * 64 + mt * 16 + l15) * 64 + kk * 32 + quad * 8];
#pragma unroll
      for (int nt = 0; nt < 4; ++nt) bf[nt] = *(const s8v*)&Bs[(wn * 64 + nt * 16 + l15) * 64 + kk * 32 + quad * 8];
#pragma unroll
      for (int mt = 0; mt < 4; ++mt)
#pragma unroll
        for (int nt = 0; nt < 4; ++nt)
          acc[mt][nt] = __builtin_amdgcn_mfma_f32_16x16x32_bf16(af[mt], bf[nt], acc[mt][nt], 0, 0, 0);
    }
    __syncthreads();
  }
#pragma unroll
  for (int nt = 0; nt < 4; ++nt) {
    const int col = n0 + wn * 64 + nt * 16 + l15;
    const float bcol = bias[col];
#pragma unroll
    for (int mt = 0; mt < 4; ++mt)
#pragma unroll
      for (int r = 0; r < 4; ++r) {
        const int row = m0 + wm * 64 + mt * 16 + quad * 4 + r;
        float v = acc[mt][nt][r] + bcol;
        if (OUT_BF16) ((short*)Cout)[row * 1024 + col] = b16(v);
        else          ((float*)Cout)[row * 1024 + col] = v;
      }
  }
}

// ---------------- V transpose: Vb [b,s,h,d] -> Vt [b,h,d,s]
__global__ __launch_bounds__(256) void vtrans(const short* __restrict__ V, short* __restrict__ Vt) {
  __shared__ short T[128][72];
  const int st = blockIdx.x, h = blockIdx.y, b = blockIdx.z;
  const int tid = threadIdx.x;
#pragma unroll
  for (int i = 0; i < 4; ++i) {
    int c = tid + i * 256;
    int r = c >> 3, c8 = (c & 7) * 8;
    *(s8v*)&T[r][c8] = *(const s8v*)&V[((b * 2048 + st * 128 + r) * 16 + h) * 64 + c8];
  }
  __syncthreads();
#pragma unroll
  for (int i = 0; i < 4; ++i) {
    int id = tid + i * 256;
    int d = id & 63, s8 = id >> 6;
    s8v o;
#pragma unroll
    for (int j = 0; j < 8; ++j) o[j] = T[s8 * 8 + j][d];
    *(s8v*)&Vt[((b * 16 + h) * 64 + d) * 2048 + st * 128 + s8 * 8] = o;
  }
}

// ---------------- fused attention v4: round-1 phase skeleton + XOR-swizzled LDS
// (3 blocks/CU) + inline l. Block = 64 q rows, 4 waves; K-tile 128.
// Swizzle: 16B chunk index XORed with (row & (chunks-1)) -> 16B-aligned, <=2-way banks.
__global__ __launch_bounds__(256, 3) void attn_ctx(const short* __restrict__ Q, const short* __restrict__ K,
                                                   const short* __restrict__ Vt,
                                                   float* __restrict__ rbuf, short* __restrict__ ctx) {
  __shared__ __align__(16) char smem[50432];
  short* Ks = (short*)smem;                 // [128 kpos][64 d]   swizzled, 16384 B
  short* Vs = (short*)(smem + 16384);       // [64 d][128 kpos]   swizzled, 16384 B
  short* Ps = (short*)(smem + 32768);       // [64 q][128 kpos]   swizzled, 16384 B
  short* Qs = Ps;                           // alias: Qs dead after frag hoist
  float* l_part = (float*)(smem + 49152);   // [4 waves][64 q]
  float* l_s    = (float*)(smem + 50176);   // [64 q] -> 1/l
  const int q64 = blockIdx.x, h = blockIdx.y, b = blockIdx.z;
  const int tid = threadIdx.x, w = tid >> 6, lane = tid & 63, quad = lane >> 4, l15 = lane & 15;
  const int bh = b * 16 + h, q0 = q64 * 64;
  const float C2 = 0.18033688011f;          // (1/8) * log2(e)

  // stage Q tile (64x64) swizzled
#pragma unroll
  for (int i = 0; i < 2; ++i) {
    int c = tid + i * 256;
    int r = c >> 3, cc = c & 7;
    *(s8v*)&Qs[r * 64 + (((cc ^ (r & 7))) << 3)] =
        *(const s8v*)&Q[((b * 2048 + q0 + r) * 16 + h) * 64 + cc * 8];
  }
  __syncthreads();
  // hoist Q fragments (B-operand of St = K·Q^T), all 64 q cols
  s8v qf[4][2];
#pragma unroll
  for (int nt = 0; nt < 4; ++nt) {
    int r = nt * 16 + l15;
    qf[nt][0] = *(const s8v*)&Qs[r * 64 + ((quad ^ (r & 7)) << 3)];
    qf[nt][1] = *(const s8v*)&Qs[r * 64 + (((4 + quad) ^ (r & 7)) << 3)];
  }
  const short* kbase = &K[((long)(b * 2048) * 16 + h) * 64];
  const short* vbase = &Vt[(long)(bh * 64) * 2048];
  f4v o[4] = {};
  float l_acc[4] = {0.f, 0.f, 0.f, 0.f};

  for (int kt = 0; kt < 16; ++kt) {
    __syncthreads();
    // stage K tile [128 kpos][64 d] and V tile [64 d][128 kpos]
#pragma unroll
    for (int i = 0; i < 4; ++i) {
      int c = tid + i * 256;
      int r = c >> 3, cc = c & 7;
      *(s8v*)&Ks[r * 64 + ((cc ^ (r & 7)) << 3)] =
          *(const s8v*)&kbase[(kt * 128 + r) * 1024 + cc * 8];
    }
#pragma unroll
    for (int i = 0; i < 4; ++i) {
      int c = tid + i * 256;
      int d = c >> 4, ck = c & 15;
      *(s8v*)&Vs[d * 128 + ((ck ^ (d & 15)) << 3)] =
          *(const s8v*)&vbase[d * 2048 + kt * 128 + ck * 8];
    }
    __syncthreads();
    // score phase: wave w computes St rows kpos [w*32, w*32+32), all 64 q
#pragma unroll
    for (int mt = 0; mt < 2; ++mt) {
      int kr = w * 32 + mt * 16 + l15;
      s8v a0 = *(const s8v*)&Ks[kr * 64 + ((quad ^ (kr & 7)) << 3)];
      s8v a1 = *(const s8v*)&Ks[kr * 64 + (((4 + quad) ^ (kr & 7)) << 3)];
#pragma unroll
      for (int nt = 0; nt < 4; ++nt) {
        f4v st = {};
        st = __builtin_amdgcn_mfma_f32_16x16x32_bf16(a0, qf[nt][0], st, 0, 0, 0);
        st = __builtin_amdgcn_mfma_f32_16x16x32_bf16(a1, qf[nt][1], st, 0, 0, 0);
        float e0 = fexp2(st[0] * C2), e1 = fexp2(st[1] * C2);
        float e2 = fexp2(st[2] * C2), e3 = fexp2(st[3] * C2);
        l_acc[nt] += (e0 + e1) + (e2 + e3);
        uint2 pp; pp.x = pk2(e0, e1); pp.y = pk2(e2, e3);
        int q = nt * 16 + l15;
        // kpos = w*32 + mt*16 + quad*4 ; chunk = kpos>>3, within = kpos&7
        int chunk = (w * 4 + mt * 2 + (quad >> 1)) ^ l15;
        *(uint2*)&Ps[q * 128 + (chunk << 3) + (quad & 1) * 4] = pp;
      }
    }
    __syncthreads();
    // PV phase: wave w owns q rows [w*16, w*16+16), full 128 kpos
#pragma unroll
    for (int kk = 0; kk < 4; ++kk) {
      int qr = w * 16 + l15;
      s8v a = *(const s8v*)&Ps[qr * 128 + (((kk * 4 + quad) ^ (qr & 15)) << 3)];
#pragma unroll
      for (int dt = 0; dt < 4; ++dt) {
        int d = dt * 16 + l15;
        s8v vb = *(const s8v*)&Vs[d * 128 + (((kk * 4 + quad) ^ (d & 15)) << 3)];
        o[dt] = __builtin_amdgcn_mfma_f32_16x16x32_bf16(a, vb, o[dt], 0, 0, 0);
      }
    }
  }

  // reduce l: intra-wave over quads, then cross-wave via LDS
#pragma unroll
  for (int nt = 0; nt < 4; ++nt) {
    float v = l_acc[nt];
    v += __shfl_xor(v, 16, 64);
    v += __shfl_xor(v, 32, 64);
    if (quad == 0) l_part[w * 64 + nt * 16 + l15] = v;
  }
  __syncthreads();
  if (tid < 64) {
    float s = l_part[tid] + l_part[64 + tid] + l_part[128 + tid] + l_part[192 + tid];
    float rv = 1.0f / s;
    l_s[tid] = rv;
    rbuf[bh * 2048 + q0 + tid] = rv;
  }
  __syncthreads();
  float rvq[4];
#pragma unroll
  for (int r = 0; r < 4; ++r) rvq[r] = l_s[w * 16 + quad * 4 + r];
#pragma unroll
  for (int dt = 0; dt < 4; ++dt)
#pragma unroll
    for (int r = 0; r < 4; ++r) {
      int sq = q0 + w * 16 + quad * 4 + r;
      ctx[((b * 2048 + sq) * 16 + h) * 64 + dt * 16 + l15] = b16(o[dt][r] * rvq[r]);
    }
}

// ---------------- mean over heads of probs -> [b, q, k] fp32 (round-2 version)
__global__ __launch_bounds__(256) void mean_probs(const short* __restrict__ Q, const short* __restrict__ K,
                                                  const float* __restrict__ rbuf, float* __restrict__ outm) {
  __shared__ short Qs[128][72];
  __shared__ short Ks[128][72];
  __shared__ float r_s[128];
  const int k128 = blockIdx.x, q128 = blockIdx.y, b = blockIdx.z;
  const int tid = threadIdx.x, w = tid >> 6, lane = tid & 63, quad = lane >> 4, l15 = lane & 15;
  f4v mn[2][8] = {};
  const float C2 = 0.18033688011f;
  for (int h = 0; h < 16; ++h) {
    __syncthreads();
#pragma unroll
    for (int i = 0; i < 4; ++i) {
      int c = tid + i * 256;
      int r = c >> 3, c8 = (c & 7) * 8;
      *(s8v*)&Qs[r][c8] = *(const s8v*)&Q[((b * 2048 + q128 * 128 + r) * 16 + h) * 64 + c8];
      *(s8v*)&Ks[r][c8] = *(const s8v*)&K[((b * 2048 + k128 * 128 + r) * 16 + h) * 64 + c8];
    }
    if (tid < 128) r_s[tid] = rbuf[(b * 16 + h) * 2048 + q128 * 128 + tid] * 0.0625f;
    __syncthreads();
    s8v aq[2][2];
#pragma unroll
    for (int qt = 0; qt < 2; ++qt) {
      aq[qt][0] = *(const s8v*)&Qs[w * 32 + qt * 16 + l15][quad * 8];
      aq[qt][1] = *(const s8v*)&Qs[w * 32 + qt * 16 + l15][32 + quad * 8];
    }
    float rr[2][4];
#pragma unroll
    for (int qt = 0; qt < 2; ++qt)
#pragma unroll
      for (int r = 0; r < 4; ++r) rr[qt][r] = r_s[w * 32 + qt * 16 + quad * 4 + r];
#pragma unroll
    for (int ktile = 0; ktile < 8; ++ktile) {
      s8v b0 = *(const s8v*)&Ks[ktile * 16 + l15][quad * 8];
      s8v b1 = *(const s8v*)&Ks[ktile * 16 + l15][32 + quad * 8];
#pragma unroll
      for (int qt = 0; qt < 2; ++qt) {
        f4v sc = {};
        sc = __builtin_amdgcn_mfma_f32_16x16x32_bf16(aq[qt][0], b0, sc, 0, 0, 0);
        sc = __builtin_amdgcn_mfma_f32_16x16x32_bf16(aq[qt][1], b1, sc, 0, 0, 0);
#pragma unroll
        for (int r = 0; r < 4; ++r)
          mn[qt][ktile][r] += fexp2(sc[r] * C2) * rr[qt][r];
      }
    }
  }
#pragma unroll
  for (int qt = 0; qt < 2; ++qt)
#pragma unroll
    for (int ktile = 0; ktile < 8; ++ktile)
#pragma unroll
      for (int r = 0; r < 4; ++r) {
        long qrow = q128 * 128 + w * 32 + qt * 16 + quad * 4 + r;
        outm[((long)b * 2048 + qrow) * 2048 + k128 * 128 + ktile * 16 + l15] = mn[qt][ktile][r];
      }
}

extern "C" void kernel_launch(void* const* d_in, const int* in_sizes, int n_in,
                              void* d_out, int out_size, void* d_ws, size_t ws_size,
                              hipStream_t stream) {
  (void)in_sizes; (void)n_in; (void)out_size; (void)ws_size;
  const float* x  = (const float*)d_in[0];
  const float* Wq = (const float*)d_in[1];
  const float* bq = (const float*)d_in[2];
  const float* Wk = (const float*)d_in[3];
  const float* bk = (const float*)d_in[4];
  const float* Wv = (const float*)d_in[5];
  const float* bv = (const float*)d_in[6];
  const float* Wo = (const float*)d_in[7];
  const float* bo = (const float*)d_in[8];
  float* out  = (float*)d_out;
  float* outm = out + 8388608;

  char* ws = (char*)d_ws;
  short* xb  = (short*)(ws);                 // 16 MB (reused as ctx)
  short* Wqt = (short*)(ws + 16777216);
  short* Wkt = (short*)(ws + 18874368);
  short* Wvt = (short*)(ws + 20971520);
  short* Wot = (short*)(ws + 23068672);
  short* Qb  = (short*)(ws + 25165824);      // 16 MB
  short* Kb  = (short*)(ws + 41943040);      // 16 MB
  short* Vb  = (short*)(ws + 58720256);      // 16 MB (dead after vtrans)
  short* Vt  = (short*)(ws + 75497472);      // 16 MB
  float* rbuf = (float*)Vb;                  // 512 KB alias in dead Vb
  short* ctx = xb;                           // alias: xb dead after QKV GEMMs

  cast_f32_bf16<<<8192, 256, 0, stream>>>(x, xb, 2097152);
  wtrans<<<512, 256, 0, stream>>>(Wq, Wqt);
  wtrans<<<512, 256, 0, stream>>>(Wk, Wkt);
  wtrans<<<512, 256, 0, stream>>>(Wv, Wvt);
  wtrans<<<512, 256, 0, stream>>>(Wo, Wot);
  dim3 gg(8, 64);
  gemm128<true><<<gg, 256, 0, stream>>>(xb, Wqt, bq, Qb);
  gemm128<true><<<gg, 256, 0, stream>>>(xb, Wkt, bk, Kb);
  gemm128<true><<<gg, 256, 0, stream>>>(xb, Wvt, bv, Vb);
  vtrans<<<dim3(16, 16, 4), 256, 0, stream>>>(Vb, Vt);
  attn_ctx<<<dim3(32, 16, 4), 256, 0, stream>>>(Qb, Kb, Vt, rbuf, ctx);
  mean_probs<<<dim3(16, 16, 4), 256, 0, stream>>>(Qb, Kb, rbuf, outm);
  gemm128<false><<<gg, 256, 0, stream>>>(ctx, Wot, bo, out);
}